// Round 2
// baseline (218.807 us; speedup 1.0000x reference)
//
#include <hip/hip_runtime.h>

#define T_LEN      1048576
#define TILE_ROWS  1024
#define NTILES     (T_LEN / TILE_ROWS)    // 1024
#define MAXO       25
#define CLAMP_HI   24.0f
#define BIGF       1e30f

#define FLAG_NONE 0u
#define FLAG_PART 1u
#define FLAG_INC  2u

// Saturating-add function f(c) = min(max(c + a, l), h); closed under composition.
struct Trip { float a, l, h; };

__device__ __forceinline__ Trip comb(Trip x, Trip y) {   // apply x first, then y
    Trip r;
    r.a = x.a + y.a;
    r.l = fmaxf(x.l + y.a, y.l);
    r.h = fminf(fmaxf(x.h + y.a, y.l), y.h);
    return r;
}
__device__ __forceinline__ float applyT(Trip p, float c) {
    return fminf(fmaxf(c + p.a, p.l), p.h);
}
__device__ __forceinline__ Trip shflUpTrip(Trip v, int off) {
    Trip r;
    r.a = __shfl_up(v.a, off, 64);
    r.l = __shfl_up(v.l, off, 64);
    r.h = __shfl_up(v.h, off, 64);
    return r;
}
__device__ __forceinline__ Trip shflTrip(Trip v, int src) {
    Trip r;
    r.a = __shfl(v.a, src, 64);
    r.l = __shfl(v.l, src, 64);
    r.h = __shfl(v.h, src, 64);
    return r;
}

// Single-pass fused kernel: per-tile scan + decoupled lookback + softmax + write.
// 1024 blocks x 256 threads; 4 rows/thread for the scan (int4 layout), then
// 4 rounds of 256 rows for softmax/staging with wave-local LDS readback.
__global__ __launch_bounds__(256)
void k_fused(const int* __restrict__ seq, const float* __restrict__ delta,
             const float* __restrict__ bias, const float* __restrict__ scale,
             unsigned* __restrict__ ticket, unsigned* __restrict__ flags,
             float* __restrict__ partA, float* __restrict__ inclA,
             float* __restrict__ out)
{
    __shared__ float tile[256 * MAXO];      // 25600 B staging (one 256-row round)
    __shared__ float c_arr[TILE_ROWS];      // 4096 B per-row counters
    __shared__ Trip  agg[4];
    __shared__ Trip  Esh;                   // exclusive tile prefix (function triple)
    __shared__ float dl[16], bs[MAXO];
    __shared__ unsigned bidsh;

    const int tid = threadIdx.x, lane = tid & 63, wid = tid >> 6;

    if (tid == 0) bidsh = atomicAdd(ticket, 1u);   // tile order == start order
    if (tid < 16)   dl[tid] = delta[tid];
    if (tid < MAXO) bs[tid] = bias[tid];
    const float sfac = scale[0];
    __syncthreads();
    const int bid = (int)bidsh;

    // ---- scan phase: thread owns rows 4*tid .. 4*tid+3 of this tile --------
    const int4 s4 = *(const int4*)(seq + bid * TILE_ROWS + tid * 4);
    const Trip t0 = {dl[s4.x], 0.0f, CLAMP_HI};
    const Trip t1 = {dl[s4.y], 0.0f, CLAMP_HI};
    const Trip t2 = {dl[s4.z], 0.0f, CLAMP_HI};
    const Trip t3 = {dl[s4.w], 0.0f, CLAMP_HI};

    Trip inc = comb(comb(t0, t1), comb(t2, t3));
#pragma unroll
    for (int off = 1; off < 64; off <<= 1) {
        Trip o = shflUpTrip(inc, off);
        if (lane >= off) inc = comb(o, inc);
    }
    if (lane == 63) agg[wid] = inc;
    __syncthreads();

    const Trip P = comb(comb(agg[0], agg[1]), comb(agg[2], agg[3]));

    // ---- decoupled lookback (wave 0 only) ----------------------------------
    if (wid == 0) {
        if (lane == 0) {
            partA[3*bid+0] = P.a; partA[3*bid+1] = P.l; partA[3*bid+2] = P.h;
            __hip_atomic_store(&flags[bid], FLAG_PART, __ATOMIC_RELEASE,
                               __HIP_MEMORY_SCOPE_AGENT);
        }
        Trip E = {0.0f, -BIGF, BIGF};        // identity
        int look = bid - 1;
        while (look >= 0) {
            const int pred = look - lane;    // lane 0 = nearest predecessor
            unsigned f = FLAG_INC;
            Trip tp = {0.0f, -BIGF, BIGF};   // virtual inclusive before tile 0
            if (pred >= 0) {
                int guard = 0;
                for (;;) {
                    f = __hip_atomic_load(&flags[pred], __ATOMIC_ACQUIRE,
                                          __HIP_MEMORY_SCOPE_AGENT);
                    if (f != FLAG_NONE || ++guard >= (1 << 20)) break;
                }
                const float* src = (f == FLAG_INC) ? (inclA + 3*pred)
                                                   : (partA + 3*pred);
                tp.a = src[0]; tp.l = src[1]; tp.h = src[2];
            }
            const unsigned long long m = __ballot(f == FLAG_INC);
            if (m) {
                const int d = __ffsll(m) - 1;          // nearest inclusive
                Trip acc = shflTrip(tp, d);            // farthest applied first
                for (int i = d - 1; i >= 0; --i) acc = comb(acc, shflTrip(tp, i));
                E = comb(acc, E);
                break;
            } else {                                   // 64 partials, keep walking
                Trip acc = shflTrip(tp, 63);
                for (int i = 62; i >= 0; --i) acc = comb(acc, shflTrip(tp, i));
                E = comb(acc, E);
                look -= 64;
            }
        }
        if (lane == 0) {
            const Trip I = comb(E, P);
            inclA[3*bid+0] = I.a; inclA[3*bid+1] = I.l; inclA[3*bid+2] = I.h;
            __hip_atomic_store(&flags[bid], FLAG_INC, __ATOMIC_RELEASE,
                               __HIP_MEMORY_SCOPE_AGENT);
            Esh = E;
        }
    }
    __syncthreads();

    // ---- per-row counters ---------------------------------------------------
    float cb = applyT(Esh, 0.0f);                      // counter entering tile
    for (int w = 0; w < wid; ++w) cb = applyT(agg[w], cb);
    const Trip prev = shflUpTrip(inc, 1);
    const float c_in = (lane == 0) ? cb : applyT(prev, cb);
    float4 cv;
    cv.x = applyT(t0, c_in);
    cv.y = applyT(t1, cv.x);
    cv.z = applyT(t2, cv.y);
    cv.w = applyT(t3, cv.z);
    *(float4*)(c_arr + 4 * tid) = cv;                  // ds_write_b128
    __syncthreads();

    // ---- softmax + staged write: 4 rounds of 256 rows, wave-local readback --
    const size_t outbase = (size_t)bid * TILE_ROWS * MAXO;
#pragma unroll 1
    for (int r = 0; r < 4; ++r) {
        const float c = c_arr[r * 256 + tid];
        float ev[MAXO];
        float sum = 0.0f;
#pragma unroll
        for (int j = 0; j < MAXO; ++j) {
            ev[j] = __expf(fmaf(-sfac, fabsf((float)j - c), bs[j]));
            sum += ev[j];
        }
        const float rinv = 1.0f / sum;
#pragma unroll
        for (int j = 0; j < MAXO; ++j)                 // stride-25: conflict-free
            tile[tid * MAXO + j] = ev[j] * rinv;

        // each wave streams out only its own 64 rows -> no __syncthreads
        const float4* tp4 = (const float4*)(tile + wid * 64 * MAXO);
        float4* op4 = (float4*)(out + outbase + (size_t)(r * 256 + wid * 64) * MAXO);
#pragma unroll
        for (int k = 0; k < 7; ++k) {
            const int idx = lane + k * 64;
            if (idx < 400) op4[idx] = tp4[idx];        // 6400 B contiguous / wave
        }
    }
}

extern "C" void kernel_launch(void* const* d_in, const int* in_sizes, int n_in,
                              void* d_out, int out_size, void* d_ws, size_t ws_size,
                              hipStream_t stream) {
    const int*   seq   = (const int*)d_in[0];
    const float* delta = (const float*)d_in[1];
    const float* bias  = (const float*)d_in[2];
    const float* scale = (const float*)d_in[3];
    float* out = (float*)d_out;

    unsigned* ticket = (unsigned*)d_ws;                  // 4 B
    unsigned* flags  = (unsigned*)((char*)d_ws + 256);   // 1024 * 4 B
    float*    partA  = (float*)((char*)d_ws + 4608);     // 1024 * 3 floats
    float*    inclA  = partA + 3 * NTILES;               // 1024 * 3 floats

    hipMemsetAsync(d_ws, 0, 4608, stream);               // ticket + flags
    k_fused<<<NTILES, 256, 0, stream>>>(seq, delta, bias, scale,
                                        ticket, flags, partA, inclA, out);
}

// Round 4
// 120.758 us; speedup vs baseline: 1.8120x; 1.8120x over previous
//
#include <hip/hip_runtime.h>

#define T_LEN      1048576
#define TILE_ROWS  1024
#define NTILES     (T_LEN / TILE_ROWS)    // 1024
#define MAXO       25
#define CLAMP_HI   24.0f
#define BIGF       1e30f

// Saturating-add function f(c) = min(max(c + a, l), h); closed under composition.
struct Trip { float a, l, h; };

__device__ __forceinline__ Trip comb(Trip x, Trip y) {   // apply x first, then y
    Trip r;
    r.a = x.a + y.a;
    r.l = fmaxf(x.l + y.a, y.l);
    r.h = fminf(fmaxf(x.h + y.a, y.l), y.h);
    return r;
}
__device__ __forceinline__ float applyT(Trip p, float c) {
    return fminf(fmaxf(c + p.a, p.l), p.h);
}
__device__ __forceinline__ Trip shflUpTrip(Trip v, int off) {
    Trip r;
    r.a = __shfl_up(v.a, off, 64);
    r.l = __shfl_up(v.l, off, 64);
    r.h = __shfl_up(v.h, off, 64);
    return r;
}

// ---------------- K1: per-tile triple (1024 blocks, 256 thr, 1 tile/block) --
__global__ __launch_bounds__(256)
void k1_tile(const int* __restrict__ seq, const float* __restrict__ delta,
             float* __restrict__ tri) {
    __shared__ float dl[16];
    __shared__ Trip agg[4];
    const int tid = threadIdx.x, lane = tid & 63, wid = tid >> 6;
    if (tid < 16) dl[tid] = delta[tid];
    __syncthreads();

    const int4 s4 = *(const int4*)(seq + blockIdx.x * TILE_ROWS + tid * 4);
    Trip t = {dl[s4.x], 0.0f, CLAMP_HI};
    { Trip e = {dl[s4.y], 0.0f, CLAMP_HI}; t = comb(t, e); }
    { Trip e = {dl[s4.z], 0.0f, CLAMP_HI}; t = comb(t, e); }
    { Trip e = {dl[s4.w], 0.0f, CLAMP_HI}; t = comb(t, e); }

#pragma unroll
    for (int off = 1; off < 64; off <<= 1) {
        Trip o = shflUpTrip(t, off);
        if (lane >= off) t = comb(o, t);
    }
    if (lane == 63) agg[wid] = t;
    __syncthreads();

    if (tid == 0) {
        const Trip P = comb(comb(agg[0], agg[1]), comb(agg[2], agg[3]));
        tri[3 * blockIdx.x + 0] = P.a;
        tri[3 * blockIdx.x + 1] = P.l;
        tri[3 * blockIdx.x + 2] = P.h;
    }
}

// ---------------- K2: redundant prefix reduction + tile scan + softmax ------
// Each block reduces tri[0..bid) itself (12 KB, L2-hot) -> no cross-block
// sync, no atomics, no spin. Then identical row/softmax/write structure.
__global__ __launch_bounds__(256)
void k2_out(const int* __restrict__ seq, const float* __restrict__ delta,
            const float* __restrict__ bias, const float* __restrict__ scale,
            const float* __restrict__ tri, float* __restrict__ out) {
    __shared__ float tile[256 * MAXO];      // 25600 B staging (one 256-row round)
    __shared__ float c_arr[TILE_ROWS];      // 4096 B per-row counters
    __shared__ Trip  agg[4], agg2[4];
    __shared__ float dl[16], bs[MAXO];

    const int tid = threadIdx.x, lane = tid & 63, wid = tid >> 6;
    const int bid = blockIdx.x;

    if (tid < 16)   dl[tid] = delta[tid];
    if (tid < MAXO) bs[tid] = bias[tid];
    const float sfac = scale[0];

    // issue both global loads early so they overlap the scans
    const int4 s4 = *(const int4*)(seq + bid * TILE_ROWS + tid * 4);
    const float4* p = (const float4*)(tri + tid * 12);   // 4 triples = 48 B
    const float4 f0 = p[0], f1 = p[1], f2 = p[2];
    __syncthreads();

    // ---- phase 1: exclusive grid prefix E = comb of tri[0..bid) ------------
    const Trip ID = {0.0f, -BIGF, BIGF};
    const int base = tid * 4;
    Trip g0 = (base + 0 < bid) ? Trip{f0.x, f0.y, f0.z} : ID;
    Trip g1 = (base + 1 < bid) ? Trip{f0.w, f1.x, f1.y} : ID;
    Trip g2 = (base + 2 < bid) ? Trip{f1.z, f1.w, f2.x} : ID;
    Trip g3 = (base + 3 < bid) ? Trip{f2.y, f2.z, f2.w} : ID;
    Trip ginc = comb(comb(g0, g1), comb(g2, g3));
#pragma unroll
    for (int off = 1; off < 64; off <<= 1) {
        Trip o = shflUpTrip(ginc, off);
        if (lane >= off) ginc = comb(o, ginc);
    }
    if (lane == 63) agg2[wid] = ginc;

    // ---- phase 2: in-tile scan (thread owns rows 4*tid .. 4*tid+3) ---------
    const Trip t0 = {dl[s4.x], 0.0f, CLAMP_HI};
    const Trip t1 = {dl[s4.y], 0.0f, CLAMP_HI};
    const Trip t2 = {dl[s4.z], 0.0f, CLAMP_HI};
    const Trip t3 = {dl[s4.w], 0.0f, CLAMP_HI};
    Trip inc = comb(comb(t0, t1), comb(t2, t3));
#pragma unroll
    for (int off = 1; off < 64; off <<= 1) {
        Trip o = shflUpTrip(inc, off);
        if (lane >= off) inc = comb(o, inc);
    }
    if (lane == 63) agg[wid] = inc;
    __syncthreads();

    const Trip E = comb(comb(agg2[0], agg2[1]), comb(agg2[2], agg2[3]));

    // ---- per-row counters ---------------------------------------------------
    float cb = applyT(E, 0.0f);                        // counter entering tile
    for (int w = 0; w < wid; ++w) cb = applyT(agg[w], cb);
    const Trip prev = shflUpTrip(inc, 1);
    const float c_in = (lane == 0) ? cb : applyT(prev, cb);
    float4 cv;
    cv.x = applyT(t0, c_in);
    cv.y = applyT(t1, cv.x);
    cv.z = applyT(t2, cv.y);
    cv.w = applyT(t3, cv.z);
    *(float4*)(c_arr + 4 * tid) = cv;                  // ds_write_b128
    __syncthreads();

    // ---- softmax + staged write: 4 rounds of 256 rows, wave-local readback --
    const size_t outbase = (size_t)bid * TILE_ROWS * MAXO;
#pragma unroll 1
    for (int r = 0; r < 4; ++r) {
        const float c = c_arr[r * 256 + tid];
        float ev[MAXO];
        float sum = 0.0f;
#pragma unroll
        for (int j = 0; j < MAXO; ++j) {
            ev[j] = __expf(fmaf(-sfac, fabsf((float)j - c), bs[j]));
            sum += ev[j];
        }
        const float rinv = 1.0f / sum;
#pragma unroll
        for (int j = 0; j < MAXO; ++j)                 // stride-25: conflict-free
            tile[tid * MAXO + j] = ev[j] * rinv;

        // each wave streams out only its own 64 rows -> no __syncthreads
        const float4* tp4 = (const float4*)(tile + wid * 64 * MAXO);
        float4* op4 = (float4*)(out + outbase + (size_t)(r * 256 + wid * 64) * MAXO);
#pragma unroll
        for (int k = 0; k < 7; ++k) {
            const int idx = lane + k * 64;
            if (idx < 400) op4[idx] = tp4[idx];        // 6400 B contiguous / wave
        }
    }
}

extern "C" void kernel_launch(void* const* d_in, const int* in_sizes, int n_in,
                              void* d_out, int out_size, void* d_ws, size_t ws_size,
                              hipStream_t stream) {
    const int*   seq   = (const int*)d_in[0];
    const float* delta = (const float*)d_in[1];
    const float* bias  = (const float*)d_in[2];
    const float* scale = (const float*)d_in[3];
    float* out = (float*)d_out;

    float* tri = (float*)d_ws;                     // NTILES*3 floats = 12 KB

    k1_tile<<<NTILES, 256, 0, stream>>>(seq, delta, tri);
    k2_out <<<NTILES, 256, 0, stream>>>(seq, delta, bias, scale, tri, out);
}